// Round 4
// baseline (553.894 us; speedup 1.0000x reference)
//
#include <hip/hip_runtime.h>
#include <cstdint>
#include <cstring>

// ---------------------------------------------------------------------------
// LinearBNNoise R4: ONE regular-launch mega-kernel + 1 memset node.
// R2's coop-launch collapse decoded from FETCH_SIZE=103GB: cooperative launch
// made wb1 (B) uncacheable -> refetched from HBM every K-step. The sync
// pattern itself was correct. So: fuse all 4 phases into a REGULAR launch
// with manual spin-barriers (device-scope atomic counters + threadfence).
// Grid 1024 x 256, __launch_bounds__(256,4), 27KB LDS -> exactly 4 blocks/CU
// -> all 1024 blocks co-resident by construction (spin is deadlock-free).
// Each block owns 64 rows; h1/h2 tiles live in LDS across barriers
// (eliminates 37.8MB of HBM round-trips + 3 dispatch gaps).
// gemm phase = R1's proven no-LDS MFMA loop, verbatim.
// ---------------------------------------------------------------------------

constexpr int MROWS = 65536;
constexpr int KDIM  = 784;
constexpr int KPAD  = 800;   // 25 * 32, zero-padded bf16 weights
constexpr int F1 = 48, F2 = 24, F3 = 10;
constexpr int NBLK = 1024;   // 64 rows/block; exactly 4 blocks/CU resident
constexpr int PREPB = 150;   // blocks participating in wb1 conversion (150*256=38400)

using frag_ab = __attribute__((ext_vector_type(8))) short;  // 8 bf16 (4 VGPRs)
using frag_cd = __attribute__((ext_vector_type(4))) float;  // 4 fp32

union UB { uint4 u; frag_ab f; };

// ---------------- threefry2x32 (20 rounds) ----------------
__device__ __forceinline__ uint32_t rotl32(uint32_t v, int r) {
  return (v << r) | (v >> (32 - r));
}

__device__ __forceinline__ uint32_t tf_mix(uint32_t k0, uint32_t k1, uint32_t ctr) {
  uint32_t ks2 = k0 ^ k1 ^ 0x1BD11BDAu;
  uint32_t x0 = k0;
  uint32_t x1 = ctr + k1;
#define TFR(r) { x0 += x1; x1 = rotl32(x1, r); x1 ^= x0; }
  TFR(13) TFR(15) TFR(26) TFR(6)
  x0 += k1;  x1 += ks2 + 1u;
  TFR(17) TFR(29) TFR(16) TFR(24)
  x0 += ks2; x1 += k0 + 2u;
  TFR(13) TFR(15) TFR(26) TFR(6)
  x0 += k0;  x1 += k1 + 3u;
  TFR(17) TFR(29) TFR(16) TFR(24)
  x0 += k1;  x1 += ks2 + 4u;
  TFR(13) TFR(15) TFR(26) TFR(6)
  x0 += ks2; x1 += k0 + 5u;
#undef TFR
  return x0 ^ x1;
}

// XLA ErfInv f32 (Giles); fast log is ~1e-6-accurate in w here.
__device__ __forceinline__ float erfinv_f32(float x) {
  float t = fmaxf(1.0f - x * x, 1.0e-30f);
  float w = -__logf(t);
  float p;
  if (w < 5.0f) {
    w = w - 2.5f;
    p = 2.81022636e-08f;
    p = fmaf(p, w, 3.43273939e-07f);
    p = fmaf(p, w, -3.5233877e-06f);
    p = fmaf(p, w, -4.39150654e-06f);
    p = fmaf(p, w, 0.00021858087f);
    p = fmaf(p, w, -0.00125372503f);
    p = fmaf(p, w, -0.00417768164f);
    p = fmaf(p, w, 0.246640727f);
    p = fmaf(p, w, 1.50140941f);
  } else {
    w = sqrtf(w) - 3.0f;
    p = -0.000200214257f;
    p = fmaf(p, w, 0.000100950558f);
    p = fmaf(p, w, 0.00134934322f);
    p = fmaf(p, w, -0.00367342844f);
    p = fmaf(p, w, 0.00573950773f);
    p = fmaf(p, w, -0.0076224613f);
    p = fmaf(p, w, 0.00943887047f);
    p = fmaf(p, w, 1.00167406f);
    p = fmaf(p, w, 2.83297682f);
  }
  return p * x;
}

__device__ __forceinline__ float noise_normal(uint32_t k0, uint32_t k1, uint32_t ctr) {
  uint32_t bits = tf_mix(k0, k1, ctr);
  float f = __uint_as_float((bits >> 9) | 0x3f800000u) - 1.0f; // [0,1)
  const float lo = -0.99999994f;
  float u = fmaxf(lo, f * 2.0f + lo);
  return 1.41421356f * erfinv_f32(u);
}

__device__ __forceinline__ uint32_t cvtpk(float a, float b) {
  uint32_t r;
  asm("v_cvt_pk_bf16_f32 %0, %1, %2" : "=v"(r) : "v"(a), "v"(b));
  return r;
}

__device__ __forceinline__ float ald(const float* p) {
  return __hip_atomic_load(p, __ATOMIC_RELAXED, __HIP_MEMORY_SCOPE_AGENT);
}

// st layout (floats): fsum1[8][48]@0  fssq1[8][48]@384
//                     fsum2[8][24]@768 fssq2[8][24]@960   (2048 total)
// fl: [0]=prep-done count, [1]=stats1 count, [2]=stats2 count
__global__ __launch_bounds__(256, 4) void k_mega(
    const float* __restrict__ x, const float* __restrict__ w1,
    const float* __restrict__ b1, const float* __restrict__ gamma1,
    const float* __restrict__ beta1, const float* __restrict__ w2,
    const float* __restrict__ b2, const float* __restrict__ gamma2,
    const float* __restrict__ beta2, const float* __restrict__ w3,
    const float* __restrict__ b3, float* __restrict__ out,
    ushort* __restrict__ wb1, float* __restrict__ st, uint32_t* __restrict__ fl,
    float u1, float u2, uint32_t kn1a, uint32_t kn1b,
    uint32_t kn2a, uint32_t kn2b) {
  __shared__ float a1s[64][49];            // h1/a1; later aliased: a2s + outs
  __shared__ float w2s[48][25];
  __shared__ float h2s[64][25];
  __shared__ float bnp[4][48];
  __shared__ float reds[4][48], redq[4][48];
  __shared__ float w3s[24][10];
  __shared__ float scal[2];

  const int t = threadIdx.x;
  const int rowbase = blockIdx.x * 64;
  const int w = t >> 6;
  const int l = t & 63;
  const int lane16 = l & 15;
  const int quad = l >> 4;
  const int myrow = rowbase + w * 16 + lane16;

  // ---- issue A preloads first (independent of wb1) ----
  const float* ap = x + (size_t)myrow * KDIM + quad * 8;
  float4 ca0 = *(const float4*)(ap);
  float4 ca1 = *(const float4*)(ap + 4);

  // ---- P0: wb1 conversion by blocks 0..149 ----
  if (blockIdx.x < PREPB) {
    int gid = blockIdx.x * 256 + t;        // 0..38399 == 48*800
    int n = gid / KPAD, k = gid - n * KPAD;
    float v = (k < KDIM) ? w1[n * KDIM + k] : 0.f;
    uint32_t u = __float_as_uint(v);
    u += 0x7fffu + ((u >> 16) & 1u);
    wb1[gid] = (ushort)(u >> 16);
    __threadfence();
  }
  __syncthreads();
  if (t == 0 && blockIdx.x < PREPB)
    __hip_atomic_fetch_add(&fl[0], 1u, __ATOMIC_RELEASE, __HIP_MEMORY_SCOPE_AGENT);
  if (t == 0) {
    while (__hip_atomic_load(&fl[0], __ATOMIC_RELAXED, __HIP_MEMORY_SCOPE_AGENT) < (uint32_t)PREPB)
      __builtin_amdgcn_s_sleep(1);
  }
  __syncthreads();
  __threadfence();

  // ---- P1: MFMA bf16 GEMM1 (R1 loop, verbatim) -> a1s LDS + stats1 ----
  {
    frag_cd acc[3];
#pragma unroll
    for (int ct = 0; ct < 3; ++ct)
#pragma unroll
      for (int r = 0; r < 4; ++r) acc[ct][r] = 0.f;

    const ushort* bp0 = wb1 + (size_t)(0 * 16 + lane16) * KPAD + quad * 8;
    const ushort* bp1 = wb1 + (size_t)(1 * 16 + lane16) * KPAD + quad * 8;
    const ushort* bp2 = wb1 + (size_t)(2 * 16 + lane16) * KPAD + quad * 8;

    uint4 cb0 = *(const uint4*)(bp0);
    uint4 cb1 = *(const uint4*)(bp1);
    uint4 cb2 = *(const uint4*)(bp2);

    for (int s = 0; s < 25; ++s) {
      float4 na0 = make_float4(0.f, 0.f, 0.f, 0.f);
      float4 na1 = na0;
      uint4 nb0 = make_uint4(0, 0, 0, 0), nb1 = nb0, nb2 = nb0;
      if (s < 24) {
        const int ko = (s + 1) * 32;
        if (ko + quad * 8 + 8 <= KDIM) {   // tail: s=24, quads 2..3 stay zero
          na0 = *(const float4*)(ap + ko);
          na1 = *(const float4*)(ap + ko + 4);
        }
        nb0 = *(const uint4*)(bp0 + ko);   // wb1 zero-padded to 800
        nb1 = *(const uint4*)(bp1 + ko);
        nb2 = *(const uint4*)(bp2 + ko);
      }
      UB a;
      a.u.x = cvtpk(ca0.x, ca0.y);
      a.u.y = cvtpk(ca0.z, ca0.w);
      a.u.z = cvtpk(ca1.x, ca1.y);
      a.u.w = cvtpk(ca1.z, ca1.w);
      UB b;
      b.u = cb0; acc[0] = __builtin_amdgcn_mfma_f32_16x16x32_bf16(a.f, b.f, acc[0], 0, 0, 0);
      b.u = cb1; acc[1] = __builtin_amdgcn_mfma_f32_16x16x32_bf16(a.f, b.f, acc[1], 0, 0, 0);
      b.u = cb2; acc[2] = __builtin_amdgcn_mfma_f32_16x16x32_bf16(a.f, b.f, acc[2], 0, 0, 0);
      ca0 = na0; ca1 = na1; cb0 = nb0; cb1 = nb1; cb2 = nb2;
    }

    // epilogue: bias, h1 -> LDS, per-feature partial stats
    float bias[3];
#pragma unroll
    for (int ct = 0; ct < 3; ++ct) bias[ct] = b1[ct * 16 + lane16];
    float psum[3] = {0.f, 0.f, 0.f}, pssq[3] = {0.f, 0.f, 0.f};
#pragma unroll
    for (int r = 0; r < 4; ++r) {
      const int lrow = w * 16 + quad * 4 + r;            // C row = quad*4+reg
#pragma unroll
      for (int ct = 0; ct < 3; ++ct) {
        float v = acc[ct][r] + bias[ct];
        a1s[lrow][ct * 16 + lane16] = v;                 // C col = lane16
        psum[ct] += v;
        pssq[ct] += v * v;
      }
    }
#pragma unroll
    for (int ct = 0; ct < 3; ++ct) {
      psum[ct] += __shfl_xor(psum[ct], 16, 64);
      psum[ct] += __shfl_xor(psum[ct], 32, 64);
      pssq[ct] += __shfl_xor(pssq[ct], 16, 64);
      pssq[ct] += __shfl_xor(pssq[ct], 32, 64);
    }
    if (quad == 0) {
#pragma unroll
      for (int ct = 0; ct < 3; ++ct) {
        reds[w][ct * 16 + lane16] = psum[ct];
        redq[w][ct * 16 + lane16] = pssq[ct];
      }
    }
  }
  __syncthreads();
  if (t < F1) {
    float s = reds[0][t] + reds[1][t] + reds[2][t] + reds[3][t];
    float q = redq[0][t] + redq[1][t] + redq[2][t] + redq[3][t];
    const int rep = blockIdx.x & 7;
    atomicAdd(&st[rep * 48 + t], s);
    atomicAdd(&st[384 + rep * 48 + t], q);
  }
  __threadfence();
  __syncthreads();
  if (t == 0)
    __hip_atomic_fetch_add(&fl[1], 1u, __ATOMIC_RELEASE, __HIP_MEMORY_SCOPE_AGENT);

  // overlap the spin: stage w2 into LDS (L2-resident)
  for (int e = t; e < F2 * 48; e += 256) {
    int c = e / 48, k = e - c * 48;
    w2s[k][c] = w2[e];
  }
  if (t == 0) {
    while (__hip_atomic_load(&fl[1], __ATOMIC_RELAXED, __HIP_MEMORY_SCOPE_AGENT) < (uint32_t)NBLK)
      __builtin_amdgcn_s_sleep(1);
  }
  __syncthreads();
  __threadfence();

  // ---- P2: BN1 finalize + noise + ReLU (in place) -> GEMM2 -> h2s + stats2 ----
  {
    float cm = 0.f, cs = 0.f;
    if (t < F1) {
      float s0 = 0.f, q0 = 0.f;
#pragma unroll
      for (int rp = 0; rp < 8; ++rp) {
        s0 += ald(&st[rp * 48 + t]);
        q0 += ald(&st[384 + rp * 48 + t]);
      }
      float m = s0 * (1.f / 65536.f);
      float v = q0 * (1.f / 65536.f) - m * m;
      float r = rsqrtf(v + 1e-5f);
      float g = gamma1[t], b = beta1[t];
      bnp[0][t] = m; bnp[1][t] = r; bnp[2][t] = g; bnp[3][t] = b;
      cm = b;
      cs = g * g * r * r * v + b * b;
    }
    if (t < 64) {
#pragma unroll
      for (int off = 32; off > 0; off >>= 1) {
        cm += __shfl_down(cm, off, 64);
        cs += __shfl_down(cs, off, 64);
      }
      if (t == 0) {
        float m = cm / (float)F1;
        float SS = 65536.f * cs;
        float Ntot = 65536.f * (float)F1;
        float s2 = (SS - Ntot * m * m) / (Ntot - 1.f);  // ddof=1
        scal[0] = m;
        scal[1] = sqrtf(s2) * u1;
      }
    }
  }
  __syncthreads();
  {
    const float m1 = scal[0], su1 = scal[1];
    const int rr = t >> 2;
    const int cc0 = (t & 3) * 12;
    const int grow = rowbase + rr;
    const uint32_t cbase = (uint32_t)grow * 48u + (uint32_t)cc0;
#pragma unroll
    for (int j = 0; j < 12; ++j) {
      int c = cc0 + j;
      float v = a1s[rr][c];
      float bn = (v - bnp[0][c]) * bnp[1][c] * bnp[2][c] + bnp[3][c];
      float nz = noise_normal(kn1a, kn1b, cbase + (uint32_t)j);
      float val = bn + fmaf(su1, nz, m1);
      a1s[rr][c] = fmaxf(val, 0.f);
    }
  }
  __syncthreads();
  {
    const int rr2 = t & 63;
    const int c0 = (t >> 6) * 6;
    float acc2[6] = {0.f, 0.f, 0.f, 0.f, 0.f, 0.f};
#pragma unroll
    for (int k = 0; k < 48; ++k) {
      float a = a1s[rr2][k];
#pragma unroll
      for (int j = 0; j < 6; ++j)
        acc2[j] = fmaf(a, w2s[k][c0 + j], acc2[j]);
    }
#pragma unroll
    for (int j = 0; j < 6; ++j)
      h2s[rr2][c0 + j] = acc2[j] + b2[c0 + j];
  }
  __syncthreads();
  // stats2: 8 chunks x 8 rows
  {
    float* redf = &reds[0][0];
    float* redqf = &redq[0][0];
    if (t < 192) {
      const int c = t % 24, ch = t / 24;
      float s = 0.f, q = 0.f;
#pragma unroll
      for (int r = ch * 8; r < ch * 8 + 8; ++r) {
        float v = h2s[r][c];
        s += v; q += v * v;
      }
      redf[ch * 24 + c] = s; redqf[ch * 24 + c] = q;
    }
    __syncthreads();
    if (t < F2) {
      float s = 0.f, q = 0.f;
#pragma unroll
      for (int ch = 0; ch < 8; ++ch) { s += redf[ch * 24 + t]; q += redqf[ch * 24 + t]; }
      const int rep = blockIdx.x & 7;
      atomicAdd(&st[768 + rep * 24 + t], s);
      atomicAdd(&st[960 + rep * 24 + t], q);
    }
  }
  __threadfence();
  __syncthreads();
  if (t == 0)
    __hip_atomic_fetch_add(&fl[2], 1u, __ATOMIC_RELEASE, __HIP_MEMORY_SCOPE_AGENT);

  // overlap the spin: stage w3
  if (t < F3 * F2) {
    int c = t / 24, k = t - c * 24;
    w3s[k][c] = w3[t];
  }
  if (t == 0) {
    while (__hip_atomic_load(&fl[2], __ATOMIC_RELAXED, __HIP_MEMORY_SCOPE_AGENT) < (uint32_t)NBLK)
      __builtin_amdgcn_s_sleep(1);
  }
  __syncthreads();
  __threadfence();

  // ---- P3: BN2 finalize + noise + ReLU -> GEMM3 -> out ----
  {
    float cm = 0.f, cs = 0.f;
    if (t < F2) {
      float s0 = 0.f, q0 = 0.f;
#pragma unroll
      for (int rp = 0; rp < 8; ++rp) {
        s0 += ald(&st[768 + rp * 24 + t]);
        q0 += ald(&st[960 + rp * 24 + t]);
      }
      float m = s0 * (1.f / 65536.f);
      float v = q0 * (1.f / 65536.f) - m * m;
      float r = rsqrtf(v + 1e-5f);
      float g = gamma2[t], b = beta2[t];
      bnp[0][t] = m; bnp[1][t] = r; bnp[2][t] = g; bnp[3][t] = b;
      cm = b;
      cs = g * g * r * r * v + b * b;
    }
    if (t < 64) {
#pragma unroll
      for (int off = 32; off > 0; off >>= 1) {
        cm += __shfl_down(cm, off, 64);
        cs += __shfl_down(cs, off, 64);
      }
      if (t == 0) {
        float m = cm / (float)F2;
        float SS = 65536.f * cs;
        float Ntot = 65536.f * (float)F2;
        float s2 = (SS - Ntot * m * m) / (Ntot - 1.f);  // ddof=1
        scal[0] = m;
        scal[1] = sqrtf(s2) * u2;
      }
    }
  }
  __syncthreads();
  // alias: a2s + outs live inside the (now dead) a1s region
  float (*a2s)[25] = reinterpret_cast<float(*)[25]>(&a1s[0][0]);
  float* outs = &a1s[0][0] + 1600;
  {
    const float m2 = scal[0], su2 = scal[1];
#pragma unroll
    for (int i = 0; i < 6; ++i) {
      int e = t + i * 256;                 // 64*24 = 1536 = 6*256
      int r = e / 24, c = e - r * 24;
      float v = h2s[r][c];
      float bn = (v - bnp[0][c]) * bnp[1][c] * bnp[2][c] + bnp[3][c];
      uint32_t ctr = (uint32_t)rowbase * 24u + (uint32_t)e;
      float nz = noise_normal(kn2a, kn2b, ctr);
      float val = bn + fmaf(su2, nz, m2);
      a2s[r][c] = fmaxf(val, 0.f);
    }
  }
  __syncthreads();
  if (t < 128) {
    const int rr = t & 63;
    const int c0 = (t >> 6) * 5;
    float acc3[5] = {0.f, 0.f, 0.f, 0.f, 0.f};
#pragma unroll
    for (int k = 0; k < 24; ++k) {
      float a = a2s[rr][k];
#pragma unroll
      for (int j = 0; j < 5; ++j)
        acc3[j] = fmaf(a, w3s[k][c0 + j], acc3[j]);
    }
#pragma unroll
    for (int j = 0; j < 5; ++j) outs[rr * F3 + c0 + j] = acc3[j] + b3[c0 + j];
  }
  __syncthreads();
  for (int e = t; e < 64 * F3; e += 256)
    out[(size_t)rowbase * F3 + e] = outs[e];
}

// ---------------- host threefry ----------------
static void host_tf(uint32_t k0, uint32_t k1, uint32_t c0, uint32_t c1,
                    uint32_t& o0, uint32_t& o1) {
  uint32_t ks2 = k0 ^ k1 ^ 0x1BD11BDAu;
  uint32_t x0 = c0 + k0, x1 = c1 + k1;
  auto R = [&](int r) { x0 += x1; x1 = (x1 << r) | (x1 >> (32 - r)); x1 ^= x0; };
  R(13); R(15); R(26); R(6);  x0 += k1;  x1 += ks2 + 1u;
  R(17); R(29); R(16); R(24); x0 += ks2; x1 += k0 + 2u;
  R(13); R(15); R(26); R(6);  x0 += k0;  x1 += k1 + 3u;
  R(17); R(29); R(16); R(24); x0 += k1;  x1 += ks2 + 4u;
  R(13); R(15); R(26); R(6);  x0 += ks2; x1 += k0 + 5u;
  o0 = x0; o1 = x1;
}

static float host_uniform12(uint32_t seed) {
  uint32_t ka, kb, t0, t1;
  host_tf(0u, seed, 0u, 0u, ka, kb);     // foldlike split, ctr 0 -> ku
  host_tf(ka, kb, 0u, 0u, t0, t1);       // random_bits of shape ()
  uint32_t bits = t0 ^ t1;               // partitionable: XOR of both words
  uint32_t fb = (bits >> 9) | 0x3f800000u;
  float f;
  std::memcpy(&f, &fb, 4);
  return f;
}

extern "C" void kernel_launch(void* const* d_in, const int* in_sizes, int n_in,
                              void* d_out, int out_size, void* d_ws, size_t ws_size,
                              hipStream_t stream) {
  (void)in_sizes; (void)n_in; (void)out_size; (void)ws_size;
  const float* x      = (const float*)d_in[0];
  const float* w1     = (const float*)d_in[1];
  const float* b1     = (const float*)d_in[2];
  const float* gamma1 = (const float*)d_in[3];
  const float* beta1  = (const float*)d_in[4];
  const float* w2     = (const float*)d_in[5];
  const float* b2     = (const float*)d_in[6];
  const float* gamma2 = (const float*)d_in[7];
  const float* beta2  = (const float*)d_in[8];
  const float* w3     = (const float*)d_in[9];
  const float* b3     = (const float*)d_in[10];
  float* out = (float*)d_out;

  float* st = (float*)d_ws;                       // 2048 floats stats
  uint32_t* fli = (uint32_t*)(st + 2048);         // 16 uints barrier flags
  ushort* wb1 = (ushort*)(st + 2048 + 16);        // 48*800 bf16

  uint32_t kn1a, kn1b, kn2a, kn2b;
  host_tf(0u, 1234u, 0u, 1u, kn1a, kn1b);         // kn of foldlike split(key(1234))
  host_tf(0u, 5678u, 0u, 1u, kn2a, kn2b);         // kn of foldlike split(key(5678))
  float u1 = host_uniform12(1234u);
  float u2 = host_uniform12(5678u);

  hipMemsetAsync(st, 0, (2048 + 16) * sizeof(float), stream);
  k_mega<<<NBLK, 256, 0, stream>>>(x, w1, b1, gamma1, beta1, w2, b2,
                                   gamma2, beta2, w3, b3, out, wb1, st, fli,
                                   u1, u2, kn1a, kn1b, kn2a, kn2b);
}

// Round 5
// 250.192 us; speedup vs baseline: 2.2139x; 2.2139x over previous
//
#include <hip/hip_runtime.h>
#include <cstdint>
#include <cstring>

// ---------------------------------------------------------------------------
// LinearBNNoise R5: 3 dispatches.
//   k_prep : w1 -> bf16 [48,800] zero-padded + zero stats/barrier block
//   k_gemm1: R1's proven no-LDS MFMA bf16 GEMM1 + per-feature stats (UNTOUCHED;
//            R4 showed spin-barrier code in the same function as the K-loop
//            poisons regalloc -> 16x collapse. Keep this kernel barrier-free.)
//   k_tail : layer2+layer3 fused. BN1 stats are ready at kernel start
//            (dispatch boundary). One spin barrier (device-scope atomic
//            counter, all 1024 blocks co-resident at 4/CU by construction)
//            between stats2-atomics and BN2-finalize. h2 tile stays in LDS:
//            saves the 12.6 MB h2 round-trip + one dispatch gap vs R1/R3.
// ---------------------------------------------------------------------------

constexpr int MROWS = 65536;
constexpr int KDIM  = 784;
constexpr int KPAD  = 800;   // 25 * 32, zero-padded bf16 weights
constexpr int F1 = 48, F2 = 24, F3 = 10;
constexpr int NBLK = 1024;   // blocks for gemm1 and tail (64 rows each)

using frag_ab = __attribute__((ext_vector_type(8))) short;  // 8 bf16 (4 VGPRs)
using frag_cd = __attribute__((ext_vector_type(4))) float;  // 4 fp32

union UB { uint4 u; frag_ab f; };

// ---------------- threefry2x32 (20 rounds) ----------------
__device__ __forceinline__ uint32_t rotl32(uint32_t v, int r) {
  return (v << r) | (v >> (32 - r));
}

// XOR of both output words of threefry2x32(key=(k0,k1), counts=(0, ctr))
__device__ __forceinline__ uint32_t tf_mix(uint32_t k0, uint32_t k1, uint32_t ctr) {
  uint32_t ks2 = k0 ^ k1 ^ 0x1BD11BDAu;
  uint32_t x0 = k0;
  uint32_t x1 = ctr + k1;
#define TFR(r) { x0 += x1; x1 = rotl32(x1, r); x1 ^= x0; }
  TFR(13) TFR(15) TFR(26) TFR(6)
  x0 += k1;  x1 += ks2 + 1u;
  TFR(17) TFR(29) TFR(16) TFR(24)
  x0 += ks2; x1 += k0 + 2u;
  TFR(13) TFR(15) TFR(26) TFR(6)
  x0 += k0;  x1 += k1 + 3u;
  TFR(17) TFR(29) TFR(16) TFR(24)
  x0 += k1;  x1 += ks2 + 4u;
  TFR(13) TFR(15) TFR(26) TFR(6)
  x0 += ks2; x1 += k0 + 5u;
#undef TFR
  return x0 ^ x1;
}

// XLA ErfInv f32 (Giles); fast log is ~1e-6-accurate in w here.
__device__ __forceinline__ float erfinv_f32(float x) {
  float t = fmaxf(1.0f - x * x, 1.0e-30f);
  float w = -__logf(t);
  float p;
  if (w < 5.0f) {
    w = w - 2.5f;
    p = 2.81022636e-08f;
    p = fmaf(p, w, 3.43273939e-07f);
    p = fmaf(p, w, -3.5233877e-06f);
    p = fmaf(p, w, -4.39150654e-06f);
    p = fmaf(p, w, 0.00021858087f);
    p = fmaf(p, w, -0.00125372503f);
    p = fmaf(p, w, -0.00417768164f);
    p = fmaf(p, w, 0.246640727f);
    p = fmaf(p, w, 1.50140941f);
  } else {
    w = sqrtf(w) - 3.0f;
    p = -0.000200214257f;
    p = fmaf(p, w, 0.000100950558f);
    p = fmaf(p, w, 0.00134934322f);
    p = fmaf(p, w, -0.00367342844f);
    p = fmaf(p, w, 0.00573950773f);
    p = fmaf(p, w, -0.0076224613f);
    p = fmaf(p, w, 0.00943887047f);
    p = fmaf(p, w, 1.00167406f);
    p = fmaf(p, w, 2.83297682f);
  }
  return p * x;
}

__device__ __forceinline__ float noise_normal(uint32_t k0, uint32_t k1, uint32_t ctr) {
  uint32_t bits = tf_mix(k0, k1, ctr);
  float f = __uint_as_float((bits >> 9) | 0x3f800000u) - 1.0f; // [0,1)
  const float lo = -0.99999994f;
  float u = fmaxf(lo, f * 2.0f + lo);
  return 1.41421356f * erfinv_f32(u);
}

// hardware packed f32->bf16 (RNE), low word = a. gfx950 has no builtin.
__device__ __forceinline__ uint32_t cvtpk(float a, float b) {
  uint32_t r;
  asm("v_cvt_pk_bf16_f32 %0, %1, %2" : "=v"(r) : "v"(a), "v"(b));
  return r;
}

__device__ __forceinline__ float ald(const float* p) {
  return __hip_atomic_load(p, __ATOMIC_RELAXED, __HIP_MEMORY_SCOPE_AGENT);
}

// ---------------- prep: w1 -> bf16 [48,800] zero-padded; zero stats+flags ------
__global__ void k_prep(const float* __restrict__ w1, ushort* __restrict__ wb1,
                       float* __restrict__ st) {
  int i = blockIdx.x * 256 + threadIdx.x;
  if (i < 2064) st[i] = 0.f;     // 8-replica stats block + barrier flags
  if (i >= F1 * KPAD) return;
  int n = i / KPAD, k = i - n * KPAD;
  float v = (k < KDIM) ? w1[n * KDIM + k] : 0.f;
  uint32_t u = __float_as_uint(v);
  u += 0x7fffu + ((u >> 16) & 1u);
  wb1[i] = (ushort)(u >> 16);
}

// ---------------- Kernel A: MFMA bf16 GEMM1, no-LDS, + per-feature stats -------
// Block: 256 thr = 4 waves, 64 rows. Wave w: rows w*16..w*16+15 x 48 cols.
// K loop: 25 steps of 32. A direct from global (2x dwordx4/lane), reg prefetch.
// Stats land in replica (blockIdx & 7) to decontend the atomics.
// R1-verbatim: NO barrier/atomic-spin code may enter this function (R4 lesson).
__global__ __launch_bounds__(256, 4) void k_gemm1(
    const float* __restrict__ x, const ushort* __restrict__ wb1,
    const float* __restrict__ b1, float* __restrict__ h1,
    float* __restrict__ fsum, float* __restrict__ fssq) {
  __shared__ float reds[4][48], redq[4][48];

  const int t = threadIdx.x;
  const int w = t >> 6;
  const int l = t & 63;
  const int lane16 = l & 15;
  const int quad = l >> 4;
  const int rowbase = blockIdx.x * 64;
  const int myrow = rowbase + w * 16 + lane16;   // A-operand row for this lane

  frag_cd acc[3];
#pragma unroll
  for (int ct = 0; ct < 3; ++ct)
#pragma unroll
    for (int r = 0; r < 4; ++r) acc[ct][r] = 0.f;

  // A: lane reads x[myrow][s*32 + quad*8 .. +7]
  const float* ap = x + (size_t)myrow * KDIM + quad * 8;
  // B: lane's column n = ct*16 + lane16, 8 contiguous k at quad*8
  const ushort* bp0 = wb1 + (size_t)(0 * 16 + lane16) * KPAD + quad * 8;
  const ushort* bp1 = wb1 + (size_t)(1 * 16 + lane16) * KPAD + quad * 8;
  const ushort* bp2 = wb1 + (size_t)(2 * 16 + lane16) * KPAD + quad * 8;

  float4 ca0 = *(const float4*)(ap);
  float4 ca1 = *(const float4*)(ap + 4);
  uint4 cb0 = *(const uint4*)(bp0);
  uint4 cb1 = *(const uint4*)(bp1);
  uint4 cb2 = *(const uint4*)(bp2);

  for (int s = 0; s < 25; ++s) {
    float4 na0 = make_float4(0.f, 0.f, 0.f, 0.f);
    float4 na1 = na0;
    uint4 nb0 = make_uint4(0, 0, 0, 0), nb1 = nb0, nb2 = nb0;
    if (s < 24) {
      const int ko = (s + 1) * 32;
      if (ko + quad * 8 + 8 <= KDIM) {   // tail: s=24, quads 2..3 stay zero
        na0 = *(const float4*)(ap + ko);
        na1 = *(const float4*)(ap + ko + 4);
      }
      nb0 = *(const uint4*)(bp0 + ko);   // wb1 zero-padded to 800
      nb1 = *(const uint4*)(bp1 + ko);
      nb2 = *(const uint4*)(bp2 + ko);
    }
    UB a;
    a.u.x = cvtpk(ca0.x, ca0.y);
    a.u.y = cvtpk(ca0.z, ca0.w);
    a.u.z = cvtpk(ca1.x, ca1.y);
    a.u.w = cvtpk(ca1.z, ca1.w);
    UB b;
    b.u = cb0; acc[0] = __builtin_amdgcn_mfma_f32_16x16x32_bf16(a.f, b.f, acc[0], 0, 0, 0);
    b.u = cb1; acc[1] = __builtin_amdgcn_mfma_f32_16x16x32_bf16(a.f, b.f, acc[1], 0, 0, 0);
    b.u = cb2; acc[2] = __builtin_amdgcn_mfma_f32_16x16x32_bf16(a.f, b.f, acc[2], 0, 0, 0);
    ca0 = na0; ca1 = na1; cb0 = nb0; cb1 = nb1; cb2 = nb2;
  }

  // epilogue: bias, store h1, per-feature sum/ssq
  float bias[3];
#pragma unroll
  for (int ct = 0; ct < 3; ++ct) bias[ct] = b1[ct * 16 + lane16];
  float psum[3] = {0.f, 0.f, 0.f}, pssq[3] = {0.f, 0.f, 0.f};
#pragma unroll
  for (int r = 0; r < 4; ++r) {
    const int grow = rowbase + w * 16 + quad * 4 + r;   // C row = quad*4+reg
#pragma unroll
    for (int ct = 0; ct < 3; ++ct) {
      float v = acc[ct][r] + bias[ct];
      h1[(size_t)grow * F1 + ct * 16 + lane16] = v;     // C col = lane16
      psum[ct] += v;
      pssq[ct] += v * v;
    }
  }
#pragma unroll
  for (int ct = 0; ct < 3; ++ct) {
    psum[ct] += __shfl_xor(psum[ct], 16, 64);
    psum[ct] += __shfl_xor(psum[ct], 32, 64);
    pssq[ct] += __shfl_xor(pssq[ct], 16, 64);
    pssq[ct] += __shfl_xor(pssq[ct], 32, 64);
  }
  if (quad == 0) {
#pragma unroll
    for (int ct = 0; ct < 3; ++ct) {
      reds[w][ct * 16 + lane16] = psum[ct];
      redq[w][ct * 16 + lane16] = pssq[ct];
    }
  }
  __syncthreads();
  if (t < F1) {
    float s = reds[0][t] + reds[1][t] + reds[2][t] + reds[3][t];
    float q = redq[0][t] + redq[1][t] + redq[2][t] + redq[3][t];
    const int rep = blockIdx.x & 7;
    atomicAdd(&fsum[rep * 48 + t], s);
    atomicAdd(&fssq[rep * 48 + t], q);
  }
}

// ---------------- Kernel B: fused layer2+layer3 with one spin barrier ---------
// BN1 finalize (stats ready at kernel start) + noise + ReLU -> GEMM2 -> h2s LDS
// + stats2 atomics -> [spin barrier over 1024 co-resident blocks] -> BN2
// finalize + noise + ReLU -> GEMM3 -> out. h2 never touches HBM.
__global__ __launch_bounds__(256, 4) void k_tail(
    const float* __restrict__ h1, const float* __restrict__ w2,
    const float* __restrict__ b2, const float* __restrict__ gamma1,
    const float* __restrict__ beta1, const float* __restrict__ gamma2,
    const float* __restrict__ beta2, const float* __restrict__ w3,
    const float* __restrict__ b3, const float* __restrict__ fsum,
    const float* __restrict__ fssq, float* __restrict__ fsum2,
    float* __restrict__ fssq2, uint32_t* __restrict__ fl,
    float u1, float u2, uint32_t kn1a, uint32_t kn1b,
    uint32_t kn2a, uint32_t kn2b, float* __restrict__ out) {
  __shared__ float a1s[64][49];        // a1; reused as a2 after the barrier
  __shared__ float w2s[48][25];
  __shared__ float h2s[64][25];
  __shared__ float bnp[4][48];
  __shared__ float w3s[24][10];
  __shared__ float scal[2];

  const int t = threadIdx.x;
  const int rowbase = blockIdx.x * 64;

  // ---- BN1 finalize (stats1 complete: dispatch boundary) ----
  {
    float cm = 0.f, cs = 0.f;
    if (t < F1) {
      float s0 = 0.f, q0 = 0.f;
#pragma unroll
      for (int rp = 0; rp < 8; ++rp) { s0 += fsum[rp * 48 + t]; q0 += fssq[rp * 48 + t]; }
      float m = s0 * (1.f / 65536.f);
      float v = q0 * (1.f / 65536.f) - m * m;
      float r = rsqrtf(v + 1e-5f);
      float g = gamma1[t], b = beta1[t];
      bnp[0][t] = m; bnp[1][t] = r; bnp[2][t] = g; bnp[3][t] = b;
      cm = b;
      cs = g * g * r * r * v + b * b;
    }
    if (t < 64) {
#pragma unroll
      for (int off = 32; off > 0; off >>= 1) {
        cm += __shfl_down(cm, off, 64);
        cs += __shfl_down(cs, off, 64);
      }
      if (t == 0) {
        float m = cm / (float)F1;
        float SS = 65536.f * cs;
        float Ntot = 65536.f * (float)F1;
        float s2 = (SS - Ntot * m * m) / (Ntot - 1.f);  // ddof=1
        scal[0] = m;
        scal[1] = sqrtf(s2) * u1;
      }
    }
    for (int e = t; e < F2 * 48; e += 256) {
      int c = e / 48, k = e - c * 48;
      w2s[k][c] = w2[e];
    }
  }
  __syncthreads();

  // ---- BN1 + noise + ReLU -> a1s ----
  {
    const float m1 = scal[0], su1 = scal[1];
    const int rr = t >> 2;
    const int cc0 = (t & 3) * 12;
    const int grow = rowbase + rr;
    const float* hrow = h1 + (size_t)grow * F1 + cc0;
    const uint32_t cbase = (uint32_t)grow * 48u + (uint32_t)cc0;
#pragma unroll
    for (int jj = 0; jj < 12; jj += 4) {
      float4 hv = *(const float4*)(hrow + jj);
      float vv[4] = {hv.x, hv.y, hv.z, hv.w};
#pragma unroll
      for (int q = 0; q < 4; ++q) {
        int c = cc0 + jj + q;
        float bn = (vv[q] - bnp[0][c]) * bnp[1][c] * bnp[2][c] + bnp[3][c];
        float nz = noise_normal(kn1a, kn1b, cbase + (uint32_t)(jj + q));
        float val = bn + fmaf(su1, nz, m1);
        a1s[rr][c] = fmaxf(val, 0.f);
      }
    }
  }
  __syncthreads();

  // ---- GEMM2 -> h2s ----
  {
    const int rr2 = t & 63;
    const int c0 = (t >> 6) * 6;
    float acc2[6] = {0.f, 0.f, 0.f, 0.f, 0.f, 0.f};
#pragma unroll
    for (int k = 0; k < 48; ++k) {
      float a = a1s[rr2][k];
#pragma unroll
      for (int j = 0; j < 6; ++j)
        acc2[j] = fmaf(a, w2s[k][c0 + j], acc2[j]);
    }
#pragma unroll
    for (int j = 0; j < 6; ++j)
      h2s[rr2][c0 + j] = acc2[j] + b2[c0 + j];
  }
  __syncthreads();

  // ---- stats2 atomics ----
  if (t < F2) {
    float s = 0.f, q = 0.f;
    for (int r2 = 0; r2 < 64; ++r2) {
      float v = h2s[r2][t];
      s += v; q += v * v;
    }
    const int rep = blockIdx.x & 7;
    atomicAdd(&fsum2[rep * 24 + t], s);
    atomicAdd(&fssq2[rep * 24 + t], q);
  }
  __threadfence();
  __syncthreads();

  // ---- spin barrier: all NBLK blocks (co-resident at 4/CU) ----
  if (t == 0)
    __hip_atomic_fetch_add(&fl[0], 1u, __ATOMIC_RELEASE, __HIP_MEMORY_SCOPE_AGENT);
  if (t < F3 * F2) {                    // overlap the wait: stage w3
    int c = t / 24, k = t - c * 24;
    w3s[k][c] = w3[t];
  }
  if (t == 0) {
    while (__hip_atomic_load(&fl[0], __ATOMIC_ACQUIRE, __HIP_MEMORY_SCOPE_AGENT) < (uint32_t)NBLK)
      __builtin_amdgcn_s_sleep(8);
  }
  __syncthreads();
  __threadfence();

  // ---- BN2 finalize ----
  {
    float cm = 0.f, cs = 0.f;
    if (t < F2) {
      float s0 = 0.f, q0 = 0.f;
#pragma unroll
      for (int rp = 0; rp < 8; ++rp) {
        s0 += ald(&fsum2[rp * 24 + t]);
        q0 += ald(&fssq2[rp * 24 + t]);
      }
      float m = s0 * (1.f / 65536.f);
      float v = q0 * (1.f / 65536.f) - m * m;
      float r = rsqrtf(v + 1e-5f);
      float g = gamma2[t], b = beta2[t];
      bnp[0][t] = m; bnp[1][t] = r; bnp[2][t] = g; bnp[3][t] = b;
      cm = b;
      cs = g * g * r * r * v + b * b;
    }
    if (t < 64) {
#pragma unroll
      for (int off = 32; off > 0; off >>= 1) {
        cm += __shfl_down(cm, off, 64);
        cs += __shfl_down(cs, off, 64);
      }
      if (t == 0) {
        float m = cm / (float)F2;
        float SS = 65536.f * cs;
        float Ntot = 65536.f * (float)F2;
        float s2 = (SS - Ntot * m * m) / (Ntot - 1.f);  // ddof=1
        scal[0] = m;
        scal[1] = sqrtf(s2) * u2;
      }
    }
  }
  __syncthreads();

  // ---- BN2 + noise + ReLU -> a2 (reuse a1s storage) ----
  {
    const float m2 = scal[0], su2 = scal[1];
#pragma unroll
    for (int i = 0; i < 6; ++i) {
      int e = t + i * 256;               // 64*24 = 1536 = 6*256
      int r = e / 24, c = e - r * 24;
      float v = h2s[r][c];
      float bn = (v - bnp[0][c]) * bnp[1][c] * bnp[2][c] + bnp[3][c];
      uint32_t ctr = (uint32_t)rowbase * 24u + (uint32_t)e;
      float nz = noise_normal(kn2a, kn2b, ctr);
      float val = bn + fmaf(su2, nz, m2);
      a1s[r][c] = fmaxf(val, 0.f);
    }
  }
  __syncthreads();

  // ---- GEMM3 -> out ----
  if (t < 128) {
    const int rr = t & 63;
    const int c0 = (t >> 6) * 5;
    float acc3[5] = {0.f, 0.f, 0.f, 0.f, 0.f};
#pragma unroll
    for (int k = 0; k < 24; ++k) {
      float a = a1s[rr][k];
#pragma unroll
      for (int j = 0; j < 5; ++j)
        acc3[j] = fmaf(a, w3s[k][c0 + j], acc3[j]);
    }
    size_t ob = (size_t)(rowbase + rr) * F3 + c0;
#pragma unroll
    for (int j = 0; j < 5; ++j) out[ob + j] = acc3[j] + b3[c0 + j];
  }
}

// ---------------- host threefry ----------------
static void host_tf(uint32_t k0, uint32_t k1, uint32_t c0, uint32_t c1,
                    uint32_t& o0, uint32_t& o1) {
  uint32_t ks2 = k0 ^ k1 ^ 0x1BD11BDAu;
  uint32_t x0 = c0 + k0, x1 = c1 + k1;
  auto R = [&](int r) { x0 += x1; x1 = (x1 << r) | (x1 >> (32 - r)); x1 ^= x0; };
  R(13); R(15); R(26); R(6);  x0 += k1;  x1 += ks2 + 1u;
  R(17); R(29); R(16); R(24); x0 += ks2; x1 += k0 + 2u;
  R(13); R(15); R(26); R(6);  x0 += k0;  x1 += k1 + 3u;
  R(17); R(29); R(16); R(24); x0 += k1;  x1 += ks2 + 4u;
  R(13); R(15); R(26); R(6);  x0 += ks2; x1 += k0 + 5u;
  o0 = x0; o1 = x1;
}

static float host_uniform12(uint32_t seed) {
  uint32_t ka, kb, t0, t1;
  host_tf(0u, seed, 0u, 0u, ka, kb);     // foldlike split, ctr 0 -> ku
  host_tf(ka, kb, 0u, 0u, t0, t1);       // random_bits of shape ()
  uint32_t bits = t0 ^ t1;               // partitionable: XOR of both words
  uint32_t fb = (bits >> 9) | 0x3f800000u;
  float f;
  std::memcpy(&f, &fb, 4);
  return f;
}

extern "C" void kernel_launch(void* const* d_in, const int* in_sizes, int n_in,
                              void* d_out, int out_size, void* d_ws, size_t ws_size,
                              hipStream_t stream) {
  (void)in_sizes; (void)n_in; (void)out_size; (void)ws_size;
  const float* x      = (const float*)d_in[0];
  const float* w1     = (const float*)d_in[1];
  const float* b1     = (const float*)d_in[2];
  const float* gamma1 = (const float*)d_in[3];
  const float* beta1  = (const float*)d_in[4];
  const float* w2     = (const float*)d_in[5];
  const float* b2     = (const float*)d_in[6];
  const float* gamma2 = (const float*)d_in[7];
  const float* beta2  = (const float*)d_in[8];
  const float* w3     = (const float*)d_in[9];
  const float* b3     = (const float*)d_in[10];
  float* out = (float*)d_out;

  float* h1 = (float*)d_ws;                       // 65536*48
  float* st = h1 + (size_t)MROWS * F1;            // stats 2048 + flags 16
  uint32_t* fli = (uint32_t*)(st + 2048);
  ushort* wb1 = (ushort*)(st + 2064);             // 48*800 bf16

  uint32_t kn1a, kn1b, kn2a, kn2b;
  host_tf(0u, 1234u, 0u, 1u, kn1a, kn1b);         // kn of foldlike split(key(1234))
  host_tf(0u, 5678u, 0u, 1u, kn2a, kn2b);         // kn of foldlike split(key(5678))
  float u1 = host_uniform12(1234u);
  float u2 = host_uniform12(5678u);

  // st layout (8 replicas each): fsum1[8][48]@0  fssq1[8][48]@384
  //                              fsum2[8][24]@768 fssq2[8][24]@960  fl@2048
  k_prep<<<(F1 * KPAD + 255) / 256, 256, 0, stream>>>(w1, wb1, st);
  k_gemm1<<<NBLK, 256, 0, stream>>>(x, wb1, b1, h1, st + 0, st + 384);
  k_tail<<<NBLK, 256, 0, stream>>>(h1, w2, b2, gamma1, beta1, gamma2, beta2,
                                   w3, b3, st + 0, st + 384, st + 768, st + 960,
                                   fli, u1, u2, kn1a, kn1b, kn2a, kn2b, out);
}

// Round 6
// 83.118 us; speedup vs baseline: 6.6640x; 3.0101x over previous
//
#include <hip/hip_runtime.h>
#include <cstdint>
#include <cstring>

// ---------------------------------------------------------------------------
// LinearBNNoise R6: R1's proven 4-dispatch structure; gemm1 rebuilt for DRAM
// efficiency. R5 measured: spin barrier ~180us (XCD cacheline ping-pong) ->
// fusion closed. gemm1 was ~50us at 4.4 TB/s (R3: not latency-bound) ->
// theory: 64K concurrent 128B-granule row-streams kill DRAM row-buffer hits.
// Fix: stage x in 6 chunks of 64 rows x 512B (double-buffered 64KB LDS,
// 2 blocks/CU), so each row advances in 512B runs and each chunk is one
// 32KB batched request burst. A-fragments from LDS with 16B-granule XOR
// swizzle sp^(row&15) (write/read matched; at the b128 bank floor).
// Per chunk: B loads (L2) issued BEFORE staging loads (HBM) so in-order
// vmcnt retirement doesn't serialize MFMA behind staging. K-tail 768..783
// = R1's masked direct-global step. Everything else R1-verbatim.
// ---------------------------------------------------------------------------

constexpr int MROWS = 65536;
constexpr int KDIM  = 784;
constexpr int KPAD  = 800;   // 25 * 32, zero-padded bf16 weights
constexpr int F1 = 48, F2 = 24, F3 = 10;
constexpr int NBLK = 1024;

using frag_ab = __attribute__((ext_vector_type(8))) short;  // 8 bf16 (4 VGPRs)
using frag_cd = __attribute__((ext_vector_type(4))) float;  // 4 fp32

union UB { uint4 u; frag_ab f; };

// ---------------- threefry2x32 (20 rounds) ----------------
__device__ __forceinline__ uint32_t rotl32(uint32_t v, int r) {
  return (v << r) | (v >> (32 - r));
}

// XOR of both output words of threefry2x32(key=(k0,k1), counts=(0, ctr))
__device__ __forceinline__ uint32_t tf_mix(uint32_t k0, uint32_t k1, uint32_t ctr) {
  uint32_t ks2 = k0 ^ k1 ^ 0x1BD11BDAu;
  uint32_t x0 = k0;
  uint32_t x1 = ctr + k1;
#define TFR(r) { x0 += x1; x1 = rotl32(x1, r); x1 ^= x0; }
  TFR(13) TFR(15) TFR(26) TFR(6)
  x0 += k1;  x1 += ks2 + 1u;
  TFR(17) TFR(29) TFR(16) TFR(24)
  x0 += ks2; x1 += k0 + 2u;
  TFR(13) TFR(15) TFR(26) TFR(6)
  x0 += k0;  x1 += k1 + 3u;
  TFR(17) TFR(29) TFR(16) TFR(24)
  x0 += k1;  x1 += ks2 + 4u;
  TFR(13) TFR(15) TFR(26) TFR(6)
  x0 += ks2; x1 += k0 + 5u;
#undef TFR
  return x0 ^ x1;
}

// XLA ErfInv f32 (Giles); fast log is ~1e-6-accurate in w here.
__device__ __forceinline__ float erfinv_f32(float x) {
  float t = fmaxf(1.0f - x * x, 1.0e-30f);
  float w = -__logf(t);
  float p;
  if (w < 5.0f) {
    w = w - 2.5f;
    p = 2.81022636e-08f;
    p = fmaf(p, w, 3.43273939e-07f);
    p = fmaf(p, w, -3.5233877e-06f);
    p = fmaf(p, w, -4.39150654e-06f);
    p = fmaf(p, w, 0.00021858087f);
    p = fmaf(p, w, -0.00125372503f);
    p = fmaf(p, w, -0.00417768164f);
    p = fmaf(p, w, 0.246640727f);
    p = fmaf(p, w, 1.50140941f);
  } else {
    w = sqrtf(w) - 3.0f;
    p = -0.000200214257f;
    p = fmaf(p, w, 0.000100950558f);
    p = fmaf(p, w, 0.00134934322f);
    p = fmaf(p, w, -0.00367342844f);
    p = fmaf(p, w, 0.00573950773f);
    p = fmaf(p, w, -0.0076224613f);
    p = fmaf(p, w, 0.00943887047f);
    p = fmaf(p, w, 1.00167406f);
    p = fmaf(p, w, 2.83297682f);
  }
  return p * x;
}

__device__ __forceinline__ float noise_normal(uint32_t k0, uint32_t k1, uint32_t ctr) {
  uint32_t bits = tf_mix(k0, k1, ctr);
  float f = __uint_as_float((bits >> 9) | 0x3f800000u) - 1.0f; // [0,1)
  const float lo = -0.99999994f;
  float u = fmaxf(lo, f * 2.0f + lo);
  return 1.41421356f * erfinv_f32(u);
}

// hardware packed f32->bf16 (RNE), low word = a. gfx950 has no builtin.
__device__ __forceinline__ uint32_t cvtpk(float a, float b) {
  uint32_t r;
  asm("v_cvt_pk_bf16_f32 %0, %1, %2" : "=v"(r) : "v"(a), "v"(b));
  return r;
}

// ---------------- prep: w1 -> bf16 [48,800] zero-padded; zero stats block -------
__global__ void k_prep(const float* __restrict__ w1, ushort* __restrict__ wb1,
                       float* __restrict__ st) {
  int i = blockIdx.x * 256 + threadIdx.x;
  if (i < 2048) st[i] = 0.f;     // 8-replica stats block
  if (i >= F1 * KPAD) return;
  int n = i / KPAD, k = i - n * KPAD;
  float v = (k < KDIM) ? w1[n * KDIM + k] : 0.f;
  uint32_t u = __float_as_uint(v);
  u += 0x7fffu + ((u >> 16) & 1u);
  wb1[i] = (ushort)(u >> 16);
}

// ---------------- Kernel A: MFMA bf16 GEMM1, LDS-staged A, + stats -------------
// Block: 256 thr = 4 waves, 64 rows, 2 blocks/CU (65.5KB LDS).
// 6 chunks x 128 floats: stage 64 rows x 512B (32KB dbuf), 4 MFMA steps/chunk
// from LDS; tail step (k=768..783) direct from global like R1's s=24.
__global__ __launch_bounds__(256, 2) void k_gemm1(
    const float* __restrict__ x, const ushort* __restrict__ wb1,
    const float* __restrict__ b1, float* __restrict__ h1,
    float* __restrict__ fsum, float* __restrict__ fssq) {
  __shared__ float xs[2][64 * 128];     // 64KB, sp-swizzled rows of 512B
  __shared__ float reds[4][48], redq[4][48];

  const int t = threadIdx.x;
  const int w = t >> 6;
  const int l = t & 63;
  const int lane16 = l & 15;
  const int quad = l >> 4;
  const int rowbase = blockIdx.x * 64;
  const int myrow = rowbase + w * 16 + lane16;   // A-operand row for this lane

  // staging role: thread stages 128B of row sr, quarter sq
  const int sr = t >> 2;
  const int sq = t & 3;
  const float* srcrow = x + (size_t)(rowbase + sr) * KDIM + sq * 32;
  const int swz = sr & 15;

  frag_cd acc[3];
#pragma unroll
  for (int ct = 0; ct < 3; ++ct)
#pragma unroll
    for (int r = 0; r < 4; ++r) acc[ct][r] = 0.f;

  // B: lane's column n = ct*16 + lane16, 8 contiguous k at quad*8
  const ushort* bp0 = wb1 + (size_t)(0 * 16 + lane16) * KPAD + quad * 8;
  const ushort* bp1 = wb1 + (size_t)(1 * 16 + lane16) * KPAD + quad * 8;
  const ushort* bp2 = wb1 + (size_t)(2 * 16 + lane16) * KPAD + quad * 8;

  // A-read LDS base: row, then per-step swizzled 16B sub-piece
  const int ardbase = (w * 16 + lane16) * 128;

  // ---- stage chunk 0 ----
  {
    float4 stg[8];
#pragma unroll
    for (int j = 0; j < 8; ++j) stg[j] = *(const float4*)(srcrow + j * 4);
#pragma unroll
    for (int j = 0; j < 8; ++j) {
      int sp = sq * 8 + j;
      *(float4*)&xs[0][sr * 128 + ((sp ^ swz) << 2)] = stg[j];
    }
  }
  __syncthreads();

  int buf = 0;
  for (int c = 0; c < 6; ++c) {
    // 1) B loads for this chunk's 4 steps (L2-resident), BEFORE staging loads
    uint4 b0[4], b1[4], b2[4];
#pragma unroll
    for (int ks = 0; ks < 4; ++ks) {
      const int ko = c * 128 + ks * 32;
      b0[ks] = *(const uint4*)(bp0 + ko);
      b1[ks] = *(const uint4*)(bp1 + ko);
      b2[ks] = *(const uint4*)(bp2 + ko);
    }
    // 2) staging loads for chunk c+1 (HBM, retire after B)
    float4 stg[8];
    if (c < 5) {
#pragma unroll
      for (int j = 0; j < 8; ++j)
        stg[j] = *(const float4*)(srcrow + (c + 1) * 128 + j * 4);
    }
    // 3) MFMA 4 steps from xs[buf]
#pragma unroll
    for (int ks = 0; ks < 4; ++ks) {
      const int sp0 = ks * 8 + quad * 2;
      float4 a0 = *(const float4*)&xs[buf][ardbase + ((sp0 ^ lane16) << 2)];
      float4 a1 = *(const float4*)&xs[buf][ardbase + (((sp0 + 1) ^ lane16) << 2)];
      UB a;
      a.u.x = cvtpk(a0.x, a0.y);
      a.u.y = cvtpk(a0.z, a0.w);
      a.u.z = cvtpk(a1.x, a1.y);
      a.u.w = cvtpk(a1.z, a1.w);
      UB b;
      b.u = b0[ks]; acc[0] = __builtin_amdgcn_mfma_f32_16x16x32_bf16(a.f, b.f, acc[0], 0, 0, 0);
      b.u = b1[ks]; acc[1] = __builtin_amdgcn_mfma_f32_16x16x32_bf16(a.f, b.f, acc[1], 0, 0, 0);
      b.u = b2[ks]; acc[2] = __builtin_amdgcn_mfma_f32_16x16x32_bf16(a.f, b.f, acc[2], 0, 0, 0);
    }
    // 4) write staged chunk c+1 into the other buffer
    if (c < 5) {
#pragma unroll
      for (int j = 0; j < 8; ++j) {
        int sp = sq * 8 + j;
        *(float4*)&xs[buf ^ 1][sr * 128 + ((sp ^ swz) << 2)] = stg[j];
      }
    }
    __syncthreads();
    buf ^= 1;
  }

  // ---- tail step s=24: k = 768..783 (quads 2..3 zero), B from 800-pad ----
  {
    float4 a0 = make_float4(0.f, 0.f, 0.f, 0.f), a1 = a0;
    if (quad < 2) {
      const float* apt = x + (size_t)myrow * KDIM + 768 + quad * 8;
      a0 = *(const float4*)(apt);
      a1 = *(const float4*)(apt + 4);
    }
    uint4 tb0 = *(const uint4*)(bp0 + 768);
    uint4 tb1 = *(const uint4*)(bp1 + 768);
    uint4 tb2 = *(const uint4*)(bp2 + 768);
    UB a;
    a.u.x = cvtpk(a0.x, a0.y);
    a.u.y = cvtpk(a0.z, a0.w);
    a.u.z = cvtpk(a1.x, a1.y);
    a.u.w = cvtpk(a1.z, a1.w);
    UB b;
    b.u = tb0; acc[0] = __builtin_amdgcn_mfma_f32_16x16x32_bf16(a.f, b.f, acc[0], 0, 0, 0);
    b.u = tb1; acc[1] = __builtin_amdgcn_mfma_f32_16x16x32_bf16(a.f, b.f, acc[1], 0, 0, 0);
    b.u = tb2; acc[2] = __builtin_amdgcn_mfma_f32_16x16x32_bf16(a.f, b.f, acc[2], 0, 0, 0);
  }

  // epilogue: bias, store h1, per-feature sum/ssq (R1-verbatim)
  float bias[3];
#pragma unroll
  for (int ct = 0; ct < 3; ++ct) bias[ct] = b1[ct * 16 + lane16];
  float psum[3] = {0.f, 0.f, 0.f}, pssq[3] = {0.f, 0.f, 0.f};
#pragma unroll
  for (int r = 0; r < 4; ++r) {
    const int grow = rowbase + w * 16 + quad * 4 + r;   // C row = quad*4+reg
#pragma unroll
    for (int ct = 0; ct < 3; ++ct) {
      float v = acc[ct][r] + bias[ct];
      h1[(size_t)grow * F1 + ct * 16 + lane16] = v;     // C col = lane16
      psum[ct] += v;
      pssq[ct] += v * v;
    }
  }
#pragma unroll
  for (int ct = 0; ct < 3; ++ct) {
    psum[ct] += __shfl_xor(psum[ct], 16, 64);
    psum[ct] += __shfl_xor(psum[ct], 32, 64);
    pssq[ct] += __shfl_xor(pssq[ct], 16, 64);
    pssq[ct] += __shfl_xor(pssq[ct], 32, 64);
  }
  if (quad == 0) {
#pragma unroll
    for (int ct = 0; ct < 3; ++ct) {
      reds[w][ct * 16 + lane16] = psum[ct];
      redq[w][ct * 16 + lane16] = pssq[ct];
    }
  }
  __syncthreads();
  if (t < F1) {
    float s = reds[0][t] + reds[1][t] + reds[2][t] + reds[3][t];
    float q = redq[0][t] + redq[1][t] + redq[2][t] + redq[3][t];
    const int rep = blockIdx.x & 7;
    atomicAdd(&fsum[rep * 48 + t], s);
    atomicAdd(&fssq[rep * 48 + t], q);
  }
}

// ---------------- Kernel C: finalize-BN1 + noise + ReLU -> GEMM2 -> stats2 -----
__global__ __launch_bounds__(256) void k_layer2(
    const float* __restrict__ h1, const float* __restrict__ w2,
    const float* __restrict__ b2, const float* __restrict__ gamma1,
    const float* __restrict__ beta1, const float* __restrict__ fsum,
    const float* __restrict__ fssq, float u1,
    float* __restrict__ h2, float* __restrict__ fsum2, float* __restrict__ fssq2,
    uint32_t kna, uint32_t knb) {
  __shared__ float a1s[64][49];
  __shared__ float w2s[48][25];
  __shared__ float h2s[64][25];
  __shared__ float bnp[4][48];
  __shared__ float scal[2];

  const int t = threadIdx.x;
  const int rowbase = blockIdx.x * 64;

  float cm = 0.f, cs = 0.f;
  if (t < F1) {
    float s0 = 0.f, q0 = 0.f;
#pragma unroll
    for (int rp = 0; rp < 8; ++rp) { s0 += fsum[rp * 48 + t]; q0 += fssq[rp * 48 + t]; }
    float m = s0 * (1.f / 65536.f);
    float v = q0 * (1.f / 65536.f) - m * m;
    float r = rsqrtf(v + 1e-5f);
    float g = gamma1[t], b = beta1[t];
    bnp[0][t] = m; bnp[1][t] = r; bnp[2][t] = g; bnp[3][t] = b;
    cm = b;
    cs = g * g * r * r * v + b * b;
  }
  if (t < 64) {
#pragma unroll
    for (int off = 32; off > 0; off >>= 1) {
      cm += __shfl_down(cm, off, 64);
      cs += __shfl_down(cs, off, 64);
    }
    if (t == 0) {
      float m = cm / (float)F1;
      float SS = 65536.f * cs;
      float Ntot = 65536.f * (float)F1;
      float s2 = (SS - Ntot * m * m) / (Ntot - 1.f);  // ddof=1
      scal[0] = m;
      scal[1] = sqrtf(s2) * u1;
    }
  }
  for (int e = t; e < F2 * 48; e += 256) {
    int c = e / 48, k = e - c * 48;
    w2s[k][c] = w2[e];
  }
  __syncthreads();
  const float m1 = scal[0], su1 = scal[1];

  const int rr = t >> 2;
  const int cc0 = (t & 3) * 12;
  const int grow = rowbase + rr;
  const float* hrow = h1 + (size_t)grow * F1 + cc0;
#pragma unroll
  for (int jj = 0; jj < 12; jj += 4) {
    float4 hv = *(const float4*)(hrow + jj);
    float vv[4] = {hv.x, hv.y, hv.z, hv.w};
#pragma unroll
    for (int q = 0; q < 4; ++q) {
      int c = cc0 + jj + q;
      float bn = (vv[q] - bnp[0][c]) * bnp[1][c] * bnp[2][c] + bnp[3][c];
      uint32_t ctr = (uint32_t)grow * 48u + (uint32_t)c;
      float nz = noise_normal(kna, knb, ctr);
      float val = bn + fmaf(su1, nz, m1);
      a1s[rr][c] = fmaxf(val, 0.f);
    }
  }
  __syncthreads();

  const int rr2 = t & 63;
  const int c0 = (t >> 6) * 6;
  float acc[6] = {0.f, 0.f, 0.f, 0.f, 0.f, 0.f};
#pragma unroll
  for (int k = 0; k < 48; ++k) {
    float a = a1s[rr2][k];
#pragma unroll
    for (int j = 0; j < 6; ++j)
      acc[j] = fmaf(a, w2s[k][c0 + j], acc[j]);
  }
#pragma unroll
  for (int j = 0; j < 6; ++j)
    h2s[rr2][c0 + j] = acc[j] + b2[c0 + j];
  __syncthreads();

  for (int e = t; e < 64 * F2; e += 256) {
    int r2 = e / 24, c2 = e - r2 * 24;
    h2[(size_t)rowbase * F2 + e] = h2s[r2][c2];
  }
  if (t < F2) {
    float s = 0.f, q = 0.f;
    for (int r2 = 0; r2 < 64; ++r2) {
      float v = h2s[r2][t];
      s += v; q += v * v;
    }
    const int rep = blockIdx.x & 7;
    atomicAdd(&fsum2[rep * 24 + t], s);
    atomicAdd(&fssq2[rep * 24 + t], q);
  }
}

// ---------------- Kernel E: finalize-BN2 + noise + ReLU -> GEMM3 -> out --------
__global__ __launch_bounds__(256) void k_layer3(
    const float* __restrict__ h2, const float* __restrict__ w3,
    const float* __restrict__ b3, const float* __restrict__ gamma2,
    const float* __restrict__ beta2, const float* __restrict__ fsum2,
    const float* __restrict__ fssq2, float u2,
    float* __restrict__ out, uint32_t kna, uint32_t knb) {
  __shared__ float a2s[64][25];
  __shared__ float w3s[24][10];
  __shared__ float bnp[4][24];
  __shared__ float scal[2];

  const int t = threadIdx.x;
  const int rowbase = blockIdx.x * 64;

  float cm = 0.f, cs = 0.f;
  if (t < F2) {
    float s0 = 0.f, q0 = 0.f;
#pragma unroll
    for (int rp = 0; rp < 8; ++rp) { s0 += fsum2[rp * 24 + t]; q0 += fssq2[rp * 24 + t]; }
    float m = s0 * (1.f / 65536.f);
    float v = q0 * (1.f / 65536.f) - m * m;
    float r = rsqrtf(v + 1e-5f);
    float g = gamma2[t], b = beta2[t];
    bnp[0][t] = m; bnp[1][t] = r; bnp[2][t] = g; bnp[3][t] = b;
    cm = b;
    cs = g * g * r * r * v + b * b;
  }
  if (t < 64) {
#pragma unroll
    for (int off = 32; off > 0; off >>= 1) {
      cm += __shfl_down(cm, off, 64);
      cs += __shfl_down(cs, off, 64);
    }
    if (t == 0) {
      float m = cm / (float)F2;
      float SS = 65536.f * cs;
      float Ntot = 65536.f * (float)F2;
      float s2 = (SS - Ntot * m * m) / (Ntot - 1.f);  // ddof=1
      scal[0] = m;
      scal[1] = sqrtf(s2) * u2;
    }
  }
  if (t < F3 * F2) {
    int c = t / 24, k = t - c * 24;
    w3s[k][c] = w3[t];
  }
  __syncthreads();
  const float m2 = scal[0], su2 = scal[1];

  for (int e = t; e < 64 * F2; e += 256) {
    int r = e / 24, c = e - r * 24;
    float v = h2[(size_t)rowbase * F2 + e];
    float bn = (v - bnp[0][c]) * bnp[1][c] * bnp[2][c] + bnp[3][c];
    uint32_t ctr = (uint32_t)(rowbase * F2 + e);
    float nz = noise_normal(kna, knb, ctr);
    float val = bn + fmaf(su2, nz, m2);
    a2s[r][c] = fmaxf(val, 0.f);
  }
  __syncthreads();

  if (t < 128) {
    const int rr = t & 63;
    const int c0 = (t >> 6) * 5;
    float acc[5] = {0.f, 0.f, 0.f, 0.f, 0.f};
#pragma unroll
    for (int k = 0; k < 24; ++k) {
      float a = a2s[rr][k];
#pragma unroll
      for (int j = 0; j < 5; ++j)
        acc[j] = fmaf(a, w3s[k][c0 + j], acc[j]);
    }
    size_t ob = (size_t)(rowbase + rr) * F3 + c0;
#pragma unroll
    for (int j = 0; j < 5; ++j) out[ob + j] = acc[j] + b3[c0 + j];
  }
}

// ---------------- host threefry ----------------
static void host_tf(uint32_t k0, uint32_t k1, uint32_t c0, uint32_t c1,
                    uint32_t& o0, uint32_t& o1) {
  uint32_t ks2 = k0 ^ k1 ^ 0x1BD11BDAu;
  uint32_t x0 = c0 + k0, x1 = c1 + k1;
  auto R = [&](int r) { x0 += x1; x1 = (x1 << r) | (x1 >> (32 - r)); x1 ^= x0; };
  R(13); R(15); R(26); R(6);  x0 += k1;  x1 += ks2 + 1u;
  R(17); R(29); R(16); R(24); x0 += ks2; x1 += k0 + 2u;
  R(13); R(15); R(26); R(6);  x0 += k0;  x1 += k1 + 3u;
  R(17); R(29); R(16); R(24); x0 += k1;  x1 += ks2 + 4u;
  R(13); R(15); R(26); R(6);  x0 += ks2; x1 += k0 + 5u;
  o0 = x0; o1 = x1;
}

static float host_uniform12(uint32_t seed) {
  uint32_t ka, kb, t0, t1;
  host_tf(0u, seed, 0u, 0u, ka, kb);     // foldlike split, ctr 0 -> ku
  host_tf(ka, kb, 0u, 0u, t0, t1);       // random_bits of shape ()
  uint32_t bits = t0 ^ t1;               // partitionable: XOR of both words
  uint32_t fb = (bits >> 9) | 0x3f800000u;
  float f;
  std::memcpy(&f, &fb, 4);
  return f;
}

extern "C" void kernel_launch(void* const* d_in, const int* in_sizes, int n_in,
                              void* d_out, int out_size, void* d_ws, size_t ws_size,
                              hipStream_t stream) {
  (void)in_sizes; (void)n_in; (void)out_size; (void)ws_size;
  const float* x      = (const float*)d_in[0];
  const float* w1     = (const float*)d_in[1];
  const float* b1     = (const float*)d_in[2];
  const float* gamma1 = (const float*)d_in[3];
  const float* beta1  = (const float*)d_in[4];
  const float* w2     = (const float*)d_in[5];
  const float* b2     = (const float*)d_in[6];
  const float* gamma2 = (const float*)d_in[7];
  const float* beta2  = (const float*)d_in[8];
  const float* w3     = (const float*)d_in[9];
  const float* b3     = (const float*)d_in[10];
  float* out = (float*)d_out;

  float* h1 = (float*)d_ws;                       // 65536*48
  float* h2 = h1 + (size_t)MROWS * F1;            // 65536*24
  float* st = h2 + (size_t)MROWS * F2;            // stats block (2048 floats)
  ushort* wb1 = (ushort*)(st + 2048);             // 48*800 bf16

  uint32_t kn1a, kn1b, kn2a, kn2b;
  host_tf(0u, 1234u, 0u, 1u, kn1a, kn1b);         // kn of foldlike split(key(1234))
  host_tf(0u, 5678u, 0u, 1u, kn2a, kn2b);         // kn of foldlike split(key(5678))
  float u1 = host_uniform12(1234u);
  float u2 = host_uniform12(5678u);

  // st layout (8 replicas each): fsum1[8][48]@0  fssq1[8][48]@384
  //                              fsum2[8][24]@768 fssq2[8][24]@960
  k_prep<<<(F1 * KPAD + 255) / 256, 256, 0, stream>>>(w1, wb1, st);
  k_gemm1<<<NBLK, 256, 0, stream>>>(x, wb1, b1, h1, st + 0, st + 384);
  k_layer2<<<NBLK, 256, 0, stream>>>(h1, w2, b2, gamma1, beta1,
                                     st + 0, st + 384, u1,
                                     h2, st + 768, st + 960, kn1a, kn1b);
  k_layer3<<<NBLK, 256, 0, stream>>>(h2, w3, b3, gamma2, beta2,
                                     st + 768, st + 960, u2,
                                     out, kn2a, kn2b);
}